// Round 7
// baseline (430.742 us; speedup 1.0000x reference)
//
#include <hip/hip_runtime.h>
#include <stdint.h>

#define HW 16384
#define CCH 256
#define NROWS 131072          // 4 pairs * 16384 px * 2 views (interleaved rows)
#define GROUP_ELEMS 524288    // 32 ch * 16384 px

typedef __attribute__((ext_vector_type(8))) short bfrag8;
typedef __attribute__((ext_vector_type(8))) unsigned short us8;
typedef __attribute__((ext_vector_type(4))) float facc4;

static __device__ __forceinline__ unsigned short f2b(float f) {
  union { float f; unsigned int u; } x; x.f = f;
  unsigned int r = x.u + 0x7FFFu + ((x.u >> 16) & 1u);
  return (unsigned short)(r >> 16);
}
static __device__ __forceinline__ float b2f(unsigned short h) {
  union { float f; unsigned int u; } x; x.u = ((unsigned int)h) << 16;
  return x.f;
}

// async global->LDS, 16B per lane: LDS dst is wave-uniform base (+lane*16 by HW),
// global src is per-lane.
static __device__ __forceinline__ void gload_lds16(const unsigned short* g, unsigned short* l) {
  __builtin_amdgcn_global_load_lds(
      (const __attribute__((address_space(1))) unsigned int*)g,
      (__attribute__((address_space(3))) unsigned int*)l, 16, 0, 0);
}

// ---------------- GroupNorm stats ----------------
__global__ void k_red(const float* __restrict__ x, float* __restrict__ red) {
  int gg = blockIdx.x >> 3, sp = blockIdx.x & 7;   // 64 groups x 8 splits
  const float4* p = (const float4*)(x + (size_t)gg * GROUP_ELEMS + (size_t)sp * 65536);
  float s = 0.f, ss = 0.f;
  for (int i = 0; i < 64; ++i) {
    float4 v = p[i * 256 + threadIdx.x];
    s  += v.x + v.y + v.z + v.w;
    ss += v.x*v.x + v.y*v.y + v.z*v.z + v.w*v.w;
  }
  for (int off = 32; off; off >>= 1) { s += __shfl_xor(s, off); ss += __shfl_xor(ss, off); }
  __shared__ float ls[4], lss[4];
  int w = threadIdx.x >> 6;
  if ((threadIdx.x & 63) == 0) { ls[w] = s; lss[w] = ss; }
  __syncthreads();
  if (threadIdx.x == 0) {
    float S = ls[0]+ls[1]+ls[2]+ls[3], SS = lss[0]+lss[1]+lss[2]+lss[3];
    atomicAdd(&red[gg*2], S); atomicAdd(&red[gg*2+1], SS);
  }
}

__global__ void k_fin(const float* __restrict__ red, float* __restrict__ stats) {
  int g = threadIdx.x;
  float s = red[g*2], ss = red[g*2+1];
  float mean = s / (float)GROUP_ELEMS;
  float var = ss / (float)GROUP_ELEMS - mean*mean;
  stats[g*2] = mean;
  stats[g*2+1] = rsqrtf(var + 1e-5f);
}

// ------- weight cast -------
// wqb fragment-major: [h][kk=0..7][j=0..11][lane][8], frag = 512 shorts.
// Fragment lane (lm,q4) holds W-row (j*16+lm), k-elems kk*32 + q4*8 + e.
// wpb fragment-major: [rb=0..1][j=0..7][kk=0..7][lane][8]:
//   lane (lm,q4) holds W-row rb*128 + j*16 + lm, k-elems kk*32 + q4*8 + e.
__global__ void k_cast(const float* __restrict__ wq, const float* __restrict__ wp,
                       unsigned short* __restrict__ wqb, unsigned short* __restrict__ wpb) {
  int i = blockIdx.x * 256 + threadIdx.x;   // grid 1024 -> 262144 = 196608 + 65536 exactly
  if (i < 768*256) {
    int h = i / 49152;
    int rem = i % 49152;
    int kk = rem / 6144;                // 0..7
    int rem2 = rem % 6144;
    int j = rem2 >> 9;                  // 0..11
    int lane = (rem2 >> 3) & 63;
    int e = rem2 & 7;
    int q4 = lane >> 4, lm = lane & 15;
    int cl = j*16 + lm;                 // head-local output col 0..191
    int part = cl >> 6, d = cl & 63;
    int o = part*256 + h*64 + d;        // original wq row
    int k = kk*32 + q4*8 + e;
    wqb[i] = f2b(wq[o*256 + k]);
  } else {
    int j2 = i - 768*256;               // 0..65535
    int rb = j2 >> 15;
    int rem = j2 & 32767;
    int jj = rem >> 12;                 // 0..7
    int kk = (rem >> 9) & 7;
    int lane = (rem >> 3) & 63;
    int e = rem & 7;
    int o = rb*128 + jj*16 + (lane & 15);
    int k = kk*32 + (lane >> 4)*8 + e;
    wpb[j2] = f2b(wp[o*256 + k]);
  }
}

// ---- norm + transpose: x[bv][c][p] fp32 -> xnt fragment-major bf16 ----
// Logical GEMM row R = pair*32768 + P*2 + v (P = pixel, v = view).
// Panel n = R>>4 (4096 shorts); within panel, kk-block (512 shorts) holds
// 16 slots x 32 channels. Slot s holds logical row 16n + sigma(s),
// sigma(s) = 2*(s&7) + (s>>3)  (view = s>>3 -> cross-view partner = lane^8).
// addr_shorts = n*4096 + kk*512 + q4*128 + s*8 + e, channel c = kk*32+q4*8+e.
__global__ void k_norm_t(const float* __restrict__ x, const float* __restrict__ stats,
                         const float* __restrict__ gamma, const float* __restrict__ beta,
                         unsigned short* __restrict__ xnt) {
  __shared__ float tile[64][65];
  int bx = blockIdx.x;               // 8192 blocks: bv(8) x ptile(256) x ctile(4)
  int bv = bx >> 10;
  int rem = bx & 1023;
  int p0 = (rem >> 2) * 64, c0 = (rem & 3) * 64;
  int pair = bv >> 1, v = bv & 1;
  int t = threadIdx.x;
  int p_off = t & 63, c4 = t >> 6;
  const float* xsrc = x + (size_t)bv * CCH * HW;
  for (int cc = 0; cc < 16; ++cc) {
    int c_loc = c4 * 16 + cc;
    int c = c0 + c_loc;
    float val = xsrc[(size_t)c * HW + p0 + p_off];
    int g = bv * 8 + (c >> 5);
    float xn = (val - stats[g*2]) * stats[g*2+1] * gamma[c] + beta[c];
    tile[p_off][c_loc] = xn;
  }
  __syncthreads();
  for (int it = 0; it < 8; ++it) {
    int u = it * 256 + t;
    int p = u >> 5, c2 = u & 31;
    int c = c0 + c2*2;
    unsigned int pk = (unsigned int)f2b(tile[p][c2*2]) | ((unsigned int)f2b(tile[p][c2*2+1]) << 16);
    int P = p0 + p;                          // pixel within pair
    int n = pair*2048 + (P >> 3);            // panel
    int s = (P & 7) + 8*v;                   // slot within panel
    size_t addr = (size_t)n*4096 + (size_t)(c >> 5)*512 + (size_t)((c & 31) >> 3)*128
                + (size_t)s*8 + (c & 7);
    *(unsigned int*)(xnt + addr) = pk;
  }
}

// ------- fused QKV GEMM + cross-view attention -------
// K-loop identical to r6 (verified). Epilogue now writes attn_out
// FRAGMENT-MAJOR in the same panel/sigma layout as xnt, so k_gemm_proj can
// load its B fragments direct-from-global as 1KB wave loads:
//   attn addr = np*4096 + kk_p*512 + q4a*128 + s*8 + e,  k = h*64 + d,
//   d = jj*16 + q4*4 + r  ->  kk_p = h*2 + (jj>>1), q4a = (jj&1)*2 + (q4>>1),
//   e = (q4&1)*4 + r  (uint2 per (i,jj), dense 512B/wave-store).
__global__ __launch_bounds__(256, 2) void k_qkv_attn(
    const unsigned short* __restrict__ A,   // xnt fragment-major
    const unsigned short* __restrict__ B,   // wqb fragment-major
    const float* __restrict__ bq,
    unsigned short* __restrict__ attn_out) {
  __shared__ __align__(16) unsigned short Blds[24 * 512];   // 24 KB
  int h = blockIdx.x;                       // head (fast dim -> A-tile L2 reuse)
  int row0 = blockIdx.y * 128;
  int t = threadIdx.x;
  int w = t >> 6, lane = t & 63;
  int lm = lane & 15, q4 = lane >> 4;

  size_t aBase = (size_t)((row0 + w*32) >> 4) * 4096 + (size_t)lane * 8;  // shorts
  const unsigned short* Bh = B + (size_t)h * 49152;

  facc4 acc[2][12];
  #pragma unroll
  for (int j = 0; j < 12; ++j) {
    facc4 bb = *(const facc4*)(bq + (j >> 2)*256 + h*64 + (j & 3)*16 + q4*4);
    acc[0][j] = bb; acc[1][j] = bb;
  }

  #pragma unroll
  for (int c = 0; c < 4; ++c) {            // 64-wide K chunks
    // stage 24 B fragments of this chunk (6 per wave), async to LDS
    #pragma unroll
    for (int i = 0; i < 6; ++i) {
      int f = w*6 + i;                     // 0..23 = kk2*12 + j
      gload_lds16(Bh + (size_t)(c*24 + f)*512 + (size_t)lane*8, &Blds[f*512]);
    }
    // prefetch the chunk's 4 A fragments (latency overlaps staging drain)
    bfrag8 a[2][2];
    #pragma unroll
    for (int kk2 = 0; kk2 < 2; ++kk2)
      #pragma unroll
      for (int p = 0; p < 2; ++p)
        a[kk2][p] = *(const bfrag8*)(A + aBase + (size_t)p*4096 + (size_t)(c*2 + kk2)*512);
    __syncthreads();                       // vmcnt(0) drain -> staged B visible
    #pragma unroll
    for (int kk2 = 0; kk2 < 2; ++kk2) {
      #pragma unroll
      for (int j = 0; j < 12; ++j) {
        bfrag8 wf = *(const bfrag8*)(&Blds[(kk2*12 + j)*512 + lane*8]);
        acc[0][j] = __builtin_amdgcn_mfma_f32_16x16x32_bf16(wf, a[kk2][0], acc[0][j], 0, 0, 0);
        acc[1][j] = __builtin_amdgcn_mfma_f32_16x16x32_bf16(wf, a[kk2][1], acc[1][j], 0, 0, 0);
      }
    }
    __syncthreads();                       // protect Blds before next chunk
  }

  // in-register cross-view attention per 16-row panel
  #pragma unroll
  for (int i = 0; i < 2; ++i) {
    // lane holds 16 of the 64 d's (d = jj*16 + q4*4 + r) for row-slot lm;
    // cross-view partner (same pixel, other view) = lane^8 under sigma order.
    float s_same = 0.f, s_cross = 0.f;
    #pragma unroll
    for (int jj = 0; jj < 4; ++jj) {
      #pragma unroll
      for (int r = 0; r < 4; ++r) {
        float qv = acc[i][jj][r];
        float kv = acc[i][4 + jj][r];
        float kx = __shfl_xor(kv, 8);
        s_same  += qv * kv;
        s_cross += qv * kx;
      }
    }
    // reduce partial dots over the 4 lane-groups (same slot in lanes l, l^16, l^32, l^48)
    s_same  += __shfl_xor(s_same, 16);  s_same  += __shfl_xor(s_same, 32);
    s_cross += __shfl_xor(s_cross, 16); s_cross += __shfl_xor(s_cross, 32);
    float s0 = s_same * 0.125f, s1 = s_cross * 0.125f;   // scale = 64^-0.5
    float m = fmaxf(s0, s1);
    float e0 = __expf(s0 - m), e1 = __expf(s1 - m);
    float inv = 1.f / (e0 + e1);
    float w_self = e0 * inv, w_cross = e1 * inv;

    int rg = row0 + w*32 + i*16;
    int np = rg >> 4;                      // panel index (slot = lm, sigma order kept)
    #pragma unroll
    for (int jj = 0; jj < 4; ++jj) {
      float o[4];
      #pragma unroll
      for (int r = 0; r < 4; ++r) {
        float vv = acc[i][8 + jj][r];
        float vx = __shfl_xor(vv, 8);
        o[r] = w_self * vv + w_cross * vx;
      }
      uint2 pk;
      pk.x = (unsigned int)f2b(o[0]) | ((unsigned int)f2b(o[1]) << 16);
      pk.y = (unsigned int)f2b(o[2]) | ((unsigned int)f2b(o[3]) << 16);
      size_t adst = (size_t)np*4096 + (size_t)(h*2 + (jj>>1))*512
                  + (size_t)((jj&1)*2 + (q4>>1))*128 + (size_t)lm*8 + (size_t)(q4&1)*4;
      *(uint2*)(attn_out + adst) = pk;
    }
  }
}

// ---- proj GEMM: out[bv][o][p] = wp[o][.] . attn[row][.] + bp[o] + x ----
// Weights (64KB, frag-major wpb) staged ONCE via global_load_lds, ONE barrier.
// B (attn) fragments load direct-from-global as 1KB wave loads (frag-major,
// written by k_qkv_attn). Wave owns 32 GEMM-rows (2 panels) x 128 o-cols:
// acc[2][8] = 64 regs. Swapped-operand MFMA (same layout as qkv). Bias in
// acc init. Epilogue decodes sigma slot -> (pair, px, view) for residual+store.
__global__ __launch_bounds__(256, 2) void k_gemm_proj(
    const unsigned short* __restrict__ Wf,  // wpb fragment-major [2][8][8][64][8]
    const unsigned short* __restrict__ Batt,// attn fragment-major
    const float* __restrict__ bias,
    const float* __restrict__ x,
    float* __restrict__ out) {
  __shared__ __align__(16) unsigned short Wlds[64 * 512];   // 64 KB
  int cb = blockIdx.x;            // 1024 col-blocks (8 panels each)
  int rb = blockIdx.y;            // o half
  int row0 = rb * 128;
  int t = threadIdx.x;
  int w = t >> 6, lane = t & 63;
  int lm = lane & 15, q4 = lane >> 4;
  int np0 = cb*8 + w*2;           // wave's 2 panels

  // stage this o-half's weights: 64 frags, 16 per wave
  #pragma unroll
  for (int i = 0; i < 16; ++i) {
    int f = w*16 + i;             // f = j*8 + kk
    gload_lds16(Wf + (size_t)rb*32768 + (size_t)f*512 + (size_t)lane*8, &Wlds[f*512]);
  }

  facc4 acc[2][8];
  #pragma unroll
  for (int j = 0; j < 8; ++j) {
    facc4 bb = *(const facc4*)(bias + row0 + j*16 + q4*4);
    acc[0][j] = bb; acc[1][j] = bb;
  }
  __syncthreads();                // staged weights visible

  #pragma unroll
  for (int kk = 0; kk < 8; ++kk) {
    bfrag8 b0 = *(const bfrag8*)(Batt + (size_t)(np0    )*4096 + (size_t)kk*512 + (size_t)lane*8);
    bfrag8 b1 = *(const bfrag8*)(Batt + (size_t)(np0 + 1)*4096 + (size_t)kk*512 + (size_t)lane*8);
    #pragma unroll
    for (int j = 0; j < 8; ++j) {
      bfrag8 wf = *(const bfrag8*)(&Wlds[(j*8 + kk)*512 + lane*8]);
      acc[0][j] = __builtin_amdgcn_mfma_f32_16x16x32_bf16(wf, b0, acc[0][j], 0, 0, 0);
      acc[1][j] = __builtin_amdgcn_mfma_f32_16x16x32_bf16(wf, b1, acc[1][j], 0, 0, 0);
    }
  }

  // epilogue: residual + store. Row = (np0+p)*16 + sigma(lm).
  #pragma unroll
  for (int p = 0; p < 2; ++p) {
    int Rl = (np0 + p)*16 + 2*(lm & 7) + (lm >> 3);
    int pair = Rl >> 15, remv = Rl & 32767;
    int px = remv >> 1, v = remv & 1;
    size_t base = ((size_t)(pair*2 + v) * 256) * 16384 + px;
    #pragma unroll
    for (int j = 0; j < 8; ++j) {
      int o0 = row0 + j*16 + q4*4;
      #pragma unroll
      for (int r = 0; r < 4; ++r) {
        size_t gidx = base + (size_t)(o0 + r) * 16384;
        out[gidx] = acc[p][j][r] + x[gidx];
      }
    }
  }
}

extern "C" void kernel_launch(void* const* d_in, const int* in_sizes, int n_in,
                              void* d_out, int out_size, void* d_ws, size_t ws_size,
                              hipStream_t stream) {
  const float* x     = (const float*)d_in[0];
  const float* gamma = (const float*)d_in[1];
  const float* beta  = (const float*)d_in[2];
  const float* wq    = (const float*)d_in[3];
  const float* bq    = (const float*)d_in[4];
  const float* wp    = (const float*)d_in[5];
  const float* bp    = (const float*)d_in[6];
  float* out = (float*)d_out;

  char* ws = (char*)d_ws;
  float* red   = (float*)ws;                    // 512 B (zeroed below)
  float* stats = (float*)(ws + 512);            // 512 B
  unsigned short* wqb = (unsigned short*)(ws + 1024);            // 393216 B (fragment-major)
  unsigned short* wpb = (unsigned short*)(ws + 1024 + 393216);   // 131072 B (fragment-major)
  size_t off = 1024 + 393216 + 131072;
  unsigned short* xnt = (unsigned short*)(ws + off); off += (size_t)NROWS * 256 * 2;  // 67 MB
  unsigned short* att = (unsigned short*)(ws + off);                                   // 67 MB

  hipMemsetAsync(red, 0, 1024, stream);
  k_cast<<<1024, 256, 0, stream>>>(wq, wp, wqb, wpb);
  k_red<<<512, 256, 0, stream>>>(x, red);
  k_fin<<<1, 64, 0, stream>>>(red, stats);
  k_norm_t<<<8192, 256, 0, stream>>>(x, stats, gamma, beta, xnt);
  k_qkv_attn<<<dim3(4, 1024), 256, 0, stream>>>(xnt, wqb, bq, att);
  k_gemm_proj<<<dim3(1024, 2), 256, 0, stream>>>(wpb, att, bp, x, out);
}